// Round 1
// baseline (804.043 us; speedup 1.0000x reference)
//
#include <hip/hip_runtime.h>
#include <cmath>

#define HH 32
#define TT 4096
#define BB 512

constexpr float F_EPS  = 1e-10f;
constexpr float F_MINV = 1e-6f;
constexpr float F_L2E  = 1.44269504088896340736f;   // log2(e)
constexpr float F_LN2  = 0.69314718055994530942f;   // ln(2)
constexpr float F_D    = 2.0f;                      // per-step log2 shift
constexpr float TWO_PI = 6.28318530717958647693f;

__global__ __launch_bounds__(64, 1)
void hmm_fwd_kernel(const float* __restrict__ obs,
                    const float* __restrict__ tlog,
                    const float* __restrict__ ilog,
                    const float* __restrict__ emean,
                    const float* __restrict__ elvar,
                    float* __restrict__ alpha,
                    float* __restrict__ ll)
{
    __shared__ __align__(16) float sA[HH * HH];
    __shared__ __align__(16) float sP[64];

    const int lane = threadIdx.x;
    const int j    = lane & 31;
    const int half = lane >> 5;
    const int b    = (int)blockIdx.x * 2 + half;
    if (b >= BB) return;

    // ---- transition softmax(+eps), written row-major to LDS by half 0 ----
    if (lane < HH) {
        float r[HH];
        #pragma unroll
        for (int k = 0; k < HH; ++k) r[k] = tlog[lane * HH + k];
        float m = r[0];
        #pragma unroll
        for (int k = 1; k < HH; ++k) m = fmaxf(m, r[k]);
        float z = 0.f;
        #pragma unroll
        for (int k = 0; k < HH; ++k) { r[k] = __expf(r[k] - m); z += r[k]; }
        float rz = 1.f / z;
        #pragma unroll
        for (int k = 0; k < HH; ++k) sA[lane * HH + k] = fmaf(r[k], rz, F_EPS);
    }
    __syncthreads();
    // per-lane column of A (A[i][j] for all i)
    float Ac[HH];
    #pragma unroll
    for (int i = 0; i < HH; ++i) Ac[i] = sA[i * HH + j];

    // ---- initial distribution: il2 = log2(softmax(ilog)[j] + eps) ----
    float il2;
    {
        float m = ilog[0];
        #pragma unroll
        for (int k = 1; k < HH; ++k) m = fmaxf(m, ilog[k]);
        float z = 0.f;
        #pragma unroll
        for (int k = 0; k < HH; ++k) z += __expf(ilog[k] - m);
        il2 = __log2f(__expf(ilog[j] - m) / z + F_EPS);
    }

    // ---- emission constants (log2 domain) ----
    const float meanj = emean[j];
    const float varj  = __expf(elvar[j]) + F_MINV;
    const float c1    = 0.5f * F_L2E / varj;
    const float c0    = -0.5f * __logf(TWO_PI * varj) * F_L2E;
    const float c0d   = c0 + F_D;

    const float*  ob  = obs + (size_t)b * TT;
    const float4* ob4 = (const float4*)ob;
    float*        ap  = alpha + (size_t)b * TT * HH + j;

    const int pbase = half * HH;
    float p, off = 0.f;

    // ---- t = 0 ----
    {
        float d  = ob[0] - meanj;
        float a2 = il2 + fmaf(d * d, -c1, c0);   // true log2 alpha0
        ap[0] = a2 * F_LN2;
        p = __builtin_amdgcn_exp2f(a2);
        ap += HH;
    }

    auto step = [&](float o) {
        float d  = o - meanj;
        float q  = fmaf(d * d, -c1, c0d);               // le2 + D (indep of chain)
        float e2 = __builtin_amdgcn_exp2f(q);
        sP[pbase + j] = p;                               // ds_write (in-order DS pipe)
        const float4* pv = (const float4*)(sP + pbase);
        float4 P[8];
        #pragma unroll
        for (int qq = 0; qq < 8; ++qq) P[qq] = pv[qq];   // 8x ds_read_b128 broadcast
        float a0 = 0.f, a1 = 0.f, a2v = 0.f, a3 = 0.f;
        #pragma unroll
        for (int qq = 0; qq < 8; ++qq) {
            a0  = fmaf(P[qq].x, Ac[4 * qq + 0], a0);
            a1  = fmaf(P[qq].y, Ac[4 * qq + 1], a1);
            a2v = fmaf(P[qq].z, Ac[4 * qq + 2], a2v);
            a3  = fmaf(P[qq].w, Ac[4 * qq + 3], a3);
        }
        float s  = (a0 + a1) + (a2v + a3);               // > 0 always
        float ls = __builtin_amdgcn_logf(s);             // v_log_f32 (log2) — output only
        p = s * e2;                                      // next scaled prob
        off -= F_D;
        *ap = (off + ls + q) * F_LN2;                    // natural-log alpha
        ap += HH;
    };

    auto renorm = [&]() {
        float m = p;
        m = fmaxf(m, __shfl_xor(m, 1, 32));
        m = fmaxf(m, __shfl_xor(m, 2, 32));
        m = fmaxf(m, __shfl_xor(m, 4, 32));
        m = fmaxf(m, __shfl_xor(m, 8, 32));
        m = fmaxf(m, __shfl_xor(m, 16, 32));
        int e;
        frexpf(m, &e);                                   // m = f * 2^e, f in [0.5,1)
        p = ldexpf(p, -e);                               // exact
        off += (float)e;                                 // exact integer accumulation
    };

    float fA[16], fB[16];
    auto loadblk = [&](float* dst, int blk) {
        float4 t0 = ob4[blk * 4 + 0];
        float4 t1 = ob4[blk * 4 + 1];
        float4 t2 = ob4[blk * 4 + 2];
        float4 t3 = ob4[blk * 4 + 3];
        dst[0]  = t0.x; dst[1]  = t0.y; dst[2]  = t0.z; dst[3]  = t0.w;
        dst[4]  = t1.x; dst[5]  = t1.y; dst[6]  = t1.z; dst[7]  = t1.w;
        dst[8]  = t2.x; dst[9]  = t2.y; dst[10] = t2.z; dst[11] = t2.w;
        dst[12] = t3.x; dst[13] = t3.y; dst[14] = t3.z; dst[15] = t3.w;
    };

    loadblk(fA, 0);
    loadblk(fB, 1);

    // prologue: t = 1..15 (block 0)
    #pragma unroll
    for (int u = 1; u < 16; ++u) { step(fA[u]); if (u == 7) renorm(); }
    renorm();
    loadblk(fA, 2);

    for (int it = 0; it < 127; ++it) {
        const int blk = 2 * it + 1;
        #pragma unroll
        for (int u = 0; u < 16; ++u) { step(fB[u]); if (u == 7) renorm(); }
        renorm();
        loadblk(fB, (blk + 2 < 256) ? (blk + 2) : 255);
        #pragma unroll
        for (int u = 0; u < 16; ++u) { step(fA[u]); if (u == 7) renorm(); }
        renorm();
        loadblk(fA, (blk + 3 < 256) ? (blk + 3) : 255);
    }
    // final block 255 (in fB): t = 4080..4095
    #pragma unroll
    for (int u = 0; u < 16; ++u) { step(fB[u]); if (u == 7) renorm(); }

    // ---- log-likelihood: logsumexp over states = log2(sum p) + off ----
    float sum = p;
    sum += __shfl_xor(sum, 1, 32);
    sum += __shfl_xor(sum, 2, 32);
    sum += __shfl_xor(sum, 4, 32);
    sum += __shfl_xor(sum, 8, 32);
    sum += __shfl_xor(sum, 16, 32);
    if (j == 0) ll[b] = (off + __builtin_amdgcn_logf(sum)) * F_LN2;
}

extern "C" void kernel_launch(void* const* d_in, const int* in_sizes, int n_in,
                              void* d_out, int out_size, void* d_ws, size_t ws_size,
                              hipStream_t stream)
{
    const float* obs = (const float*)d_in[0];
    const float* tl  = (const float*)d_in[1];
    const float* il  = (const float*)d_in[2];
    const float* em  = (const float*)d_in[3];
    const float* ev  = (const float*)d_in[4];
    float* alpha = (float*)d_out;
    float* ll    = alpha + (size_t)BB * TT * HH;
    hmm_fwd_kernel<<<BB / 2, 64, 0, stream>>>(obs, tl, il, em, ev, alpha, ll);
}

// Round 5
// 676.886 us; speedup vs baseline: 1.1879x; 1.1879x over previous
//
#include <hip/hip_runtime.h>
#include <cmath>

#define HH 32
#define TT 4096
#define BB 512

typedef float v2 __attribute__((ext_vector_type(2)));

constexpr float F_EPS  = 1e-10f;
constexpr float F_MINV = 1e-6f;
constexpr float F_L2E  = 1.44269504088896340736f;   // log2(e)
constexpr float F_LN2  = 0.69314718055994530942f;   // ln(2)
constexpr float TWO_PI = 6.28318530717958647693f;

__global__ __launch_bounds__(64, 1)
void hmm_row4_kernel(const float* __restrict__ obs,
                     const float* __restrict__ tlog,
                     const float* __restrict__ ilog,
                     const float* __restrict__ emean,
                     const float* __restrict__ elvar,
                     float* __restrict__ alpha,
                     float* __restrict__ ll)
{
    __shared__ __align__(16) float sA[HH * HH];
    __shared__ __align__(16) v2    sP[4 * 20];   // 4 rows, stride 20 v2 = 160 B (bank-disjoint rows)

    const int lane = threadIdx.x;
    const int r    = lane & 15;          // lane within row
    const int ro   = lane >> 4;          // row = chain within block
    const int b    = (int)blockIdx.x * 4 + ro;
    const int j0   = 2 * r;              // this lane's two states: j0, j0+1

    // ---- transition softmax(+eps), rows built by lanes 0..31 ----
    if (lane < HH) {
        float rw[HH];
        #pragma unroll
        for (int k = 0; k < HH; ++k) rw[k] = tlog[lane * HH + k];
        float m = rw[0];
        #pragma unroll
        for (int k = 1; k < HH; ++k) m = fmaxf(m, rw[k]);
        float z = 0.f;
        #pragma unroll
        for (int k = 0; k < HH; ++k) { rw[k] = __expf(rw[k] - m); z += rw[k]; }
        float rz = 1.f / z;
        #pragma unroll
        for (int k = 0; k < HH; ++k) sA[lane * HH + k] = fmaf(rw[k], rz, F_EPS);
    }
    __syncthreads();

    // ---- per-lane A slices: AJ0[m] = (A[2m][j0], A[2m+1][j0]), AJ1 same for j0+1 ----
    v2 AJ0[16], AJ1[16];
    #pragma unroll
    for (int m = 0; m < 16; ++m) {
        AJ0[m] = v2{ sA[(2*m)*HH + j0],     sA[(2*m+1)*HH + j0]     };
        AJ1[m] = v2{ sA[(2*m)*HH + j0 + 1], sA[(2*m+1)*HH + j0 + 1] };
    }

    // ---- initial distribution (log2 domain), per-lane pair ----
    v2 il2;
    {
        float m = ilog[0];
        #pragma unroll
        for (int k = 1; k < HH; ++k) m = fmaxf(m, ilog[k]);
        float z = 0.f;
        #pragma unroll
        for (int k = 0; k < HH; ++k) z += __expf(ilog[k] - m);
        float rz = 1.f / z;
        il2 = v2{ __log2f(__expf(ilog[j0]     - m) * rz + F_EPS),
                  __log2f(__expf(ilog[j0 + 1] - m) * rz + F_EPS) };
    }

    // ---- emission constants (log2 domain), per-lane pair ----
    const v2 mm = v2{ emean[j0], emean[j0 + 1] };
    const float vx = __expf(elvar[j0])     + F_MINV;
    const float vy = __expf(elvar[j0 + 1]) + F_MINV;
    const v2 c1 = v2{ 0.5f * F_L2E / vx, 0.5f * F_L2E / vy };
    const v2 c0 = v2{ -0.5f * __logf(TWO_PI * vx) * F_L2E,
                      -0.5f * __logf(TWO_PI * vy) * F_L2E };

    const float* ob = obs + (size_t)b * TT;
    float*       ap = alpha + (size_t)b * TT * HH + j0;

    v2 pp; float off = 0.f;

    // ---- t = 0 ----
    {
        float o = ob[0];
        v2 d = v2{ o - mm.x, o - mm.y };
        v2 q = v2{ fmaf(d.x * d.x, -c1.x, c0.x), fmaf(d.y * d.y, -c1.y, c0.y) };
        v2 a2 = il2 + q;
        ap[0] = a2.x * F_LN2; ap[1] = a2.y * F_LN2;
        pp = v2{ __builtin_amdgcn_exp2f(a2.x), __builtin_amdgcn_exp2f(a2.y) };
        ap += HH;
    }

    // ---- emission pipeline: slot(t) = t&7 holds (q_t, e2_t); obuf slot(t&3) holds ob[t+8] ----
    v2 Qs[8], E2s[8];
    #pragma unroll
    for (int u = 0; u < 8; ++u) {
        float o = ob[1 + u];
        v2 d = v2{ o - mm.x, o - mm.y };
        v2 q = v2{ fmaf(d.x * d.x, -c1.x, c0.x), fmaf(d.y * d.y, -c1.y, c0.y) };
        Qs[(1 + u) & 7]  = q;
        E2s[(1 + u) & 7] = v2{ __builtin_amdgcn_exp2f(q.x), __builtin_amdgcn_exp2f(q.y) };
    }
    float obuf[4];
    obuf[1] = ob[9]; obuf[2] = ob[10]; obuf[3] = ob[11]; obuf[0] = ob[12];

    v2* const rowP = &sP[ro * 20];
    const float4* const rowP4 = (const float4*)rowP;

    // ---- main loop body (macro keeps all indices compile-time static) ----
#define HMM_STEP(T_, U8_, U4_, RENORM_, PF_)                                        \
    {                                                                               \
        rowP[r] = pp;                                                               \
        v2 P2[16];                                                                  \
        _Pragma("unroll")                                                           \
        for (int qq = 0; qq < 8; ++qq) {                                            \
            float4 f = rowP4[qq];                                                   \
            P2[2*qq]   = v2{ f.x, f.y };                                            \
            P2[2*qq+1] = v2{ f.z, f.w };                                            \
        }                                                                           \
        v2 aA0{0,0}, aA1{0,0}, aA2{0,0}, aA3{0,0};                                  \
        v2 aB0{0,0}, aB1{0,0}, aB2{0,0}, aB3{0,0};                                  \
        _Pragma("unroll")                                                           \
        for (int m = 0; m < 16; m += 4) {                                           \
            aA0 = __builtin_elementwise_fma(P2[m+0], AJ0[m+0], aA0);                \
            aB0 = __builtin_elementwise_fma(P2[m+0], AJ1[m+0], aB0);                \
            aA1 = __builtin_elementwise_fma(P2[m+1], AJ0[m+1], aA1);                \
            aB1 = __builtin_elementwise_fma(P2[m+1], AJ1[m+1], aB1);                \
            aA2 = __builtin_elementwise_fma(P2[m+2], AJ0[m+2], aA2);                \
            aB2 = __builtin_elementwise_fma(P2[m+2], AJ1[m+2], aB2);                \
            aA3 = __builtin_elementwise_fma(P2[m+3], AJ0[m+3], aA3);                \
            aB3 = __builtin_elementwise_fma(P2[m+3], AJ1[m+3], aB3);                \
        }                                                                           \
        v2 sa = (aA0 + aA1) + (aA2 + aA3);                                          \
        v2 sb = (aB0 + aB1) + (aB2 + aB3);                                          \
        float s0 = sa.x + sa.y;                                                     \
        float s1 = sb.x + sb.y;                                                     \
        v2 qv  = Qs[(U8_)];                                                         \
        v2 e2v = E2s[(U8_)];                                                        \
        v2 np = v2{ s0 * e2v.x, s1 * e2v.y };                                       \
        float l0 = __builtin_amdgcn_logf(s0);                                       \
        float l1 = __builtin_amdgcn_logf(s1);                                       \
        ap[0] = (off + qv.x + l0) * F_LN2;                                          \
        ap[1] = (off + qv.y + l1) * F_LN2;                                          \
        ap += HH;                                                                   \
        if (RENORM_) {                                                              \
            v2 x0 = __builtin_elementwise_max(__builtin_elementwise_max(P2[0], P2[1]),   \
                                              __builtin_elementwise_max(P2[2], P2[3]));  \
            v2 x1 = __builtin_elementwise_max(__builtin_elementwise_max(P2[4], P2[5]),   \
                                              __builtin_elementwise_max(P2[6], P2[7]));  \
            v2 x2 = __builtin_elementwise_max(__builtin_elementwise_max(P2[8], P2[9]),   \
                                              __builtin_elementwise_max(P2[10], P2[11]));\
            v2 x3 = __builtin_elementwise_max(__builtin_elementwise_max(P2[12], P2[13]), \
                                              __builtin_elementwise_max(P2[14], P2[15]));\
            v2 xm = __builtin_elementwise_max(__builtin_elementwise_max(x0, x1),    \
                                              __builtin_elementwise_max(x2, x3));   \
            float mx = fmaxf(xm.x, xm.y);                                           \
            int ee; frexpf(mx, &ee);                                                \
            float sc = ldexpf(1.0f, -ee);                                           \
            np = v2{ np.x * sc, np.y * sc };                                        \
            off += (float)ee;                                                       \
        }                                                                           \
        pp = np;                                                                    \
        {                                                                           \
            float o = obuf[(U4_)];                                                  \
            v2 d  = v2{ o - mm.x, o - mm.y };                                       \
            v2 nq = v2{ fmaf(d.x*d.x, -c1.x, c0.x), fmaf(d.y*d.y, -c1.y, c0.y) };   \
            Qs[(U8_)]  = nq;                                                        \
            E2s[(U8_)] = v2{ __builtin_amdgcn_exp2f(nq.x),                          \
                             __builtin_amdgcn_exp2f(nq.y) };                        \
        }                                                                           \
        obuf[(U4_)] = ob[(PF_)];                                                    \
    }

    // main: t = 1 .. 4080 (255 blocks of 16); slot phases depend only on k
    for (int blk = 0; blk < 255; ++blk) {
        const int t0 = 1 + blk * 16;
        #pragma unroll
        for (int k = 0; k < 16; ++k) {
            HMM_STEP(t0 + k, ((1 + k) & 7), ((1 + k) & 3), (((1 + k) & 7) == 0), (t0 + k + 12));
        }
    }
    // epilogue: t = 4081 .. 4095 (prefetch index clamped; dead slots harmless)
    #pragma unroll
    for (int k = 0; k < 15; ++k) {
        const int t  = 4081 + k;
        const int pf = (4093 + k <= 4095) ? (4093 + k) : 4095;
        HMM_STEP(t, ((t) & 7), ((t) & 3), (((t) & 7) == 0), pf);
    }
#undef HMM_STEP

    // ---- log-likelihood: ln2 * (off + log2 sum_j pp_j), reduce across the 16-lane row ----
    float sfin = pp.x + pp.y;
    sfin += __shfl_xor(sfin, 1, 16);
    sfin += __shfl_xor(sfin, 2, 16);
    sfin += __shfl_xor(sfin, 4, 16);
    sfin += __shfl_xor(sfin, 8, 16);
    if (r == 0) ll[b] = (off + __builtin_amdgcn_logf(sfin)) * F_LN2;
}

extern "C" void kernel_launch(void* const* d_in, const int* in_sizes, int n_in,
                              void* d_out, int out_size, void* d_ws, size_t ws_size,
                              hipStream_t stream)
{
    const float* obs = (const float*)d_in[0];
    const float* tl  = (const float*)d_in[1];
    const float* il  = (const float*)d_in[2];
    const float* em  = (const float*)d_in[3];
    const float* ev  = (const float*)d_in[4];
    float* alpha = (float*)d_out;
    float* ll    = alpha + (size_t)BB * TT * HH;
    hmm_row4_kernel<<<BB / 4, 64, 0, stream>>>(obs, tl, il, em, ev, alpha, ll);
}